// Round 7
// baseline (57.886 us; speedup 1.0000x reference)
//
#include <hip/hip_runtime.h>

// Separable cubic-B-spline coefficient->value filter:
// out = F_D(F_H(F_W(coeff))), 3-tap [1/6, 4/6, 1/6], zero padding.
// Shape: (B*C=4, D=160, H=192, W=160), fp32.
//
// R7: same z-column sliding window as R6 (double-buffered raw-slice regs,
// structural 1-iteration load->use distance), but ZC 10 -> 5 to double the
// wave count (3840 -> 7680 waves; fills ~94% of the 8192 chip wave slots).
// R6 was stall-bound: per-SIMD latency cover ~3.75 waves x 200cy < HBM
// latency. 6 resident waves/SIMD x 200cy now exceeds it.

typedef float f32x4 __attribute__((ext_vector_type(4)));

static constexpr int Dd = 160;
static constexpr int Hh = 192;
static constexpr int Ww = 160;
static constexpr int BC = 4;
static constexpr int HW = Hh * Ww;

static constexpr float KW1 = 1.0f / 6.0f;
static constexpr float KW0 = 2.0f / 3.0f;

static constexpr int ZC  = 5;         // z outputs per thread
static constexpr int NZC = Dd / ZC;   // 32 chunks

// Load raw slice S (z = z0+S, clamped; OOB handled by zero z-weights) into buf B.
#define LOAD_SLICE(B, S)                                                  \
    do {                                                                  \
        int zs_ = z0 + (S);                                               \
        zs_ = zs_ < 0 ? 0 : (zs_ >= Dd ? Dd - 1 : zs_);                   \
        const float* p_ = base_bc + (size_t)zs_ * HW;                     \
        _Pragma("unroll")                                                 \
        for (int dy_ = 0; dy_ < 3; ++dy_) {                               \
            const float* row_ = p_ + yterm[dy_];                          \
            ra[B][dy_] = *reinterpret_cast<const f32x4*>(row_);           \
            rb[B][dy_] = *reinterpret_cast<const f32x4*>(row_ + 4);       \
            rl[B][dy_] = row_[offL];                                      \
            rr[B][dy_] = row_[offR];                                      \
        }                                                                 \
    } while (0)

// y-filter buf B into yfb[SLOT] (10-wide y-filtered row at w0-1..w0+8).
#define YFILTER(SLOT, B)                                                  \
    do {                                                                  \
        float* yf_ = yfb[SLOT];                                           \
        yf_[0] = mL * (cyw[0] * rl[B][0] + cyw[1] * rl[B][1] +            \
                       cyw[2] * rl[B][2]);                                \
        yf_[9] = mR * (cyw[0] * rr[B][0] + cyw[1] * rr[B][1] +            \
                       cyw[2] * rr[B][2]);                                \
        _Pragma("unroll")                                                 \
        for (int k_ = 0; k_ < 4; ++k_) {                                  \
            yf_[1 + k_] = cyw[0] * ra[B][0][k_] + cyw[1] * ra[B][1][k_] + \
                          cyw[2] * ra[B][2][k_];                          \
            yf_[5 + k_] = cyw[0] * rb[B][0][k_] + cyw[1] * rb[B][1][k_] + \
                          cyw[2] * rb[B][2][k_];                          \
        }                                                                 \
    } while (0)

__global__ __launch_bounds__(256, 2) void CoeffToValue_kernel(
    const float* __restrict__ in, float* __restrict__ out)
{
    const int idx = blockIdx.x * 256 + threadIdx.x;
    const int wc = idx % 20;
    const int r1 = idx / 20;
    const int y  = r1 % Hh;
    const int r2 = r1 / Hh;
    const int zc = r2 % NZC;
    const int bc = r2 / NZC;

    const int z0 = zc * ZC;
    const int w0 = wc * 8;

    // y taps: clamped row offsets, OOB folded into zeroed weights.
    int yterm[3];
    float cyw[3];
    {
        const float wy[3] = {KW1, KW0, KW1};
#pragma unroll
        for (int dy = 0; dy < 3; ++dy) {
            int ys = y + dy - 1;
            const float ok = (ys >= 0 && ys < Hh) ? 1.0f : 0.0f;
            ys = ys < 0 ? 0 : (ys >= Hh ? Hh - 1 : ys);
            yterm[dy] = ys * Ww;
            cyw[dy] = wy[dy] * ok;
        }
    }

    const float* base_bc = in + (size_t)bc * Dd * HW + w0;
    const int offL = (w0 > 0) ? -1 : 0;          // clamped w-edge offsets
    const int offR = (w0 + 8 < Ww) ? 8 : 7;
    const float mL = (w0 > 0) ? 1.0f : 0.0f;     // w-edge zero masks
    const float mR = (w0 + 8 < Ww) ? 1.0f : 0.0f;

    // Double-buffered raw slice (3 y-rows x 10 floats) + 3-slot yf ring.
    f32x4 ra[2][3], rb[2][3];
    float rl[2][3], rr[2][3];
    float yfb[3][10];

    // Prologue. raw[s] lives in buffer s&1 (s=-1 -> buf 1).
    LOAD_SLICE(1, -1);
    LOAD_SLICE(0, 0);
    YFILTER(2, 1);            // slice -1 -> slot 2
    LOAD_SLICE(1, 1);
    YFILTER(0, 0);            // slice  0 -> slot 0

    float* orow = out + (((size_t)bc * Dd + z0) * Hh + y) * Ww + w0;

#pragma unroll
    for (int i = 0; i < ZC; ++i) {
        // Prefetch raw slice i+2 (not needed past slice ZC).
        if (i + 2 <= ZC) {
            if ((i & 1) == 0) { LOAD_SLICE(0, i + 2); }
            else              { LOAD_SLICE(1, i + 2); }
        }
        // y-filter slice i+1 (loaded one iteration ago, buffer (i+1)&1).
        {
            const int sp_ = (i + 1) % 3;
            if (((i + 1) & 1) == 0) { YFILTER(sp_, 0); }
            else                    { YFILTER(sp_, 1); }
        }

        // z-filter (edge slices get zero weight; their clamped data is finite).
        const int z = z0 + i;
        const float czm = (z > 0)      ? KW1 : 0.0f;
        const float czp = (z < Dd - 1) ? KW1 : 0.0f;
        const int sm = (i + 2) % 3;   // slot(i-1)
        const int s0 = i % 3;
        const int sp = (i + 1) % 3;

        float t[10];
#pragma unroll
        for (int j = 0; j < 10; ++j)
            t[j] = fmaf(czm, yfb[sm][j],
                   fmaf(KW0, yfb[s0][j], czp * yfb[sp][j]));

        // w-filter, two aligned float4 stores.
        f32x4 oa, ob;
#pragma unroll
        for (int k = 0; k < 4; ++k) {
            oa[k] = fmaf(KW1, t[k],     fmaf(KW0, t[k + 1], KW1 * t[k + 2]));
            ob[k] = fmaf(KW1, t[k + 4], fmaf(KW0, t[k + 5], KW1 * t[k + 6]));
        }
        *reinterpret_cast<f32x4*>(orow)     = oa;
        *reinterpret_cast<f32x4*>(orow + 4) = ob;
        orow += (size_t)HW;
    }
}

extern "C" void kernel_launch(void* const* d_in, const int* in_sizes, int n_in,
                              void* d_out, int out_size, void* d_ws, size_t ws_size,
                              hipStream_t stream) {
    const float* in = (const float*)d_in[0];
    float* out = (float*)d_out;

    // threads = 4 (bc) * 32 (z-chunks) * 192 (y) * 20 (w-chunks) = 491,520
    const int total  = BC * NZC * Hh * (Ww / 8);
    const int blocks = total / 256;               // 1920
    CoeffToValue_kernel<<<blocks, 256, 0, stream>>>(in, out);
}

// Round 8
// 34.059 us; speedup vs baseline: 1.6996x; 1.6996x over previous
//
#include <hip/hip_runtime.h>

// Separable cubic-B-spline coefficient->value filter:
// out = F_D(F_H(F_W(coeff))), 3-tap [1/6, 4/6, 1/6], zero padding.
// Shape: (B*C=4, D=160, H=192, W=160), fp32.
//
// R8: cooperative LDS staging via global_load_lds (direct-to-LDS DMA).
// Block tile: (bc, 16 y, 8 z) x full W. Ring of 2 slice patches in LDS,
// staged one-ahead; per-thread yf ring in registers. In-flight bytes live
// in LDS instead of VGPRs -> HBM pipeline depth no longer fights occupancy
// (R5-R7 were Little's-law-capped at ~2.5 TB/s by VGPR-resident prefetch).

typedef float f32x2 __attribute__((ext_vector_type(2)));

static constexpr int Dd = 160, Hh = 192, Ww = 160, BC = 4;
static constexpr int Zt = 8, Yt = 16;
static constexpr int NZB = Dd / Zt;   // 20
static constexpr int NYB = Hh / Yt;   // 12
static constexpr float KW1 = 1.0f / 6.0f;
static constexpr float KW0 = 2.0f / 3.0f;

// LDS patch: 18 rows, stride 164 floats (16B multiple: global_load_lds dest
// must be 16B aligned), 4-float front pad so w0-2 reads never go negative.
static constexpr int ROWF   = 164;
static constexpr int PATCHF = 18 * ROWF;   // 2952 floats = 11,808 B

__device__ __forceinline__ void gload16(const float* g, float* l) {
    // 64 lanes x 16B: global per-lane address, LDS = uniform base + lane*16.
    __builtin_amdgcn_global_load_lds(
        (const __attribute__((address_space(1))) float*)g,
        (__attribute__((address_space(3))) float*)l, 16, 0, 0);
}

struct YF { float v[12]; };   // y-filtered row at w = w0-1 .. w0+10

__global__ __launch_bounds__(256) void CoeffToValue_kernel(
    const float* __restrict__ in, float* __restrict__ out)
{
    __shared__ __align__(16) float lds[2 * PATCHF + 4];

    const int tid  = threadIdx.x;
    const int lane = tid & 63;
    const int wave = tid >> 6;
    const int wc   = tid & 15;     // w-chunk: outputs [10*wc, 10*wc+10)
    const int yo   = tid >> 4;     // y-output within tile: 0..15

    const int bid = blockIdx.x;
    const int zc  = bid % NZB;
    const int yb  = (bid / NZB) % NYB;
    const int bc  = bid / (NZB * NYB);
    const int z0  = zc * Zt;
    const int y0  = yb * Yt;

    // y-tap weights; zero-padded boundary folded into weights. The patch
    // holds clamped (finite) duplicate rows at the edges, weight 0 kills them.
    float cyw[3];
    {
        const float wy[3] = {KW1, KW0, KW1};
#pragma unroll
        for (int dy = 0; dy < 3; ++dy) {
            const int g = y0 + yo + dy - 1;
            cyw[dy] = (g >= 0 && g < Hh) ? wy[dy] : 0.0f;
        }
    }

    const size_t plane = (size_t)Hh * Ww;
    const float* inb = in + (size_t)bc * Dd * plane;

    // Stage slice z0+k (z clamped) into LDS slot k&1. Row-wise: 40 lanes x
    // 16B = one 640B row per instruction; rows clamped independently at the
    // y boundary so patch row p always equals "requested row y0-1+p".
    auto stage = [&](int k) {
        int zs = z0 + k;
        zs = zs < 0 ? 0 : (zs >= Dd ? Dd - 1 : zs);
        const float* sp = inb + (size_t)zs * plane;
        float* slot = lds + (k & 1) * PATCHF;
        if (lane < 40) {
            for (int p = wave; p < 18; p += 4) {
                int ys = y0 - 1 + p;
                ys = ys < 0 ? 0 : (ys >= Hh ? Hh - 1 : ys);
                gload16(sp + (size_t)ys * Ww + lane * 4, slot + p * ROWF + 4);
            }
        }
    };

    // y-filter slice z0+k at this thread's (yo, wc) from LDS -> YF (regs).
    // Reads 7 aligned float2 per row (w0-2 .. w0+11); v[1..12] used.
    auto yfilter = [&](int k) -> YF {
        const float* base = lds + (k & 1) * PATCHF + 10 * wc + 2;
        YF o;
#pragma unroll
        for (int q = 0; q < 12; ++q) o.v[q] = 0.0f;
#pragma unroll
        for (int dy = 0; dy < 3; ++dy) {
            const float* rp = base + (yo + dy) * ROWF;
            float v[14];
#pragma unroll
            for (int r = 0; r < 7; ++r) {
                f32x2 p2 = *reinterpret_cast<const f32x2*>(rp + 2 * r);
                v[2 * r] = p2.x; v[2 * r + 1] = p2.y;
            }
            const float c = cyw[dy];
#pragma unroll
            for (int q = 0; q < 12; ++q) o.v[q] = fmaf(c, v[q + 1], o.v[q]);
        }
        return o;
    };

    // --- warmup: slices z0-1, z0 resident; yf ring primed; slice z0+1 landing
    stage(-1); stage(0);
    __syncthreads();                 // both patches resident
    YF a = yfilter(-1);              // yf(z0-1)
    YF b = yfilter(0);               // yf(z0)
    __syncthreads();                 // all reads of slot1 done
    stage(1);                        // slice z0+1 -> slot1
    __syncthreads();                 // slice z0+1 resident

#pragma unroll
    for (int i = 0; i < Zt; ++i) {
        // prefetch slice i+2 into the slot slice i just vacated
        if (i < Zt - 1) stage(i + 2);

        YF n = yfilter(i + 1);       // fresh yf(z+1) from resident patch

        const int z = z0 + i;
        const float czm = (z > 0)      ? KW1 : 0.0f;
        const float czp = (z < Dd - 1) ? KW1 : 0.0f;

        float t[12];
#pragma unroll
        for (int q = 0; q < 12; ++q)
            t[q] = fmaf(czm, a.v[q], fmaf(KW0, b.v[q], czp * n.v[q]));
        // w-boundary: select (not multiply) so stale-LDS NaN cannot leak
        t[0]  = (wc > 0)  ? t[0]  : 0.0f;
        t[11] = (wc < 15) ? t[11] : 0.0f;

        float* orow = out + ((size_t)(bc * Dd + z) * Hh + (y0 + yo)) * Ww + 10 * wc;
#pragma unroll
        for (int s = 0; s < 5; ++s) {
            f32x2 o2;
            o2.x = fmaf(KW0, t[2 * s + 1], KW1 * (t[2 * s]     + t[2 * s + 2]));
            o2.y = fmaf(KW0, t[2 * s + 2], KW1 * (t[2 * s + 1] + t[2 * s + 3]));
            *reinterpret_cast<f32x2*>(orow + 2 * s) = o2;
        }

        a = b; b = n;                // rotate yf ring (reg-resident)

        if (i < Zt - 1) __syncthreads();   // drains prefetch; frees next slot
    }
}

extern "C" void kernel_launch(void* const* d_in, const int* in_sizes, int n_in,
                              void* d_out, int out_size, void* d_ws, size_t ws_size,
                              hipStream_t stream) {
    const float* in = (const float*)d_in[0];
    float* out = (float*)d_out;

    const int blocks = BC * NYB * NZB;   // 4*12*20 = 960
    CoeffToValue_kernel<<<blocks, 256, 0, stream>>>(in, out);
}

// Round 9
// 33.481 us; speedup vs baseline: 1.7289x; 1.0172x over previous
//
#include <hip/hip_runtime.h>

// Separable cubic-B-spline coefficient->value filter:
// out = F_D(F_H(F_W(coeff))), 3-tap [1/6, 4/6, 1/6], zero padding.
// Shape: (B*C=4, D=160, H=192, W=160), fp32.
//
// R9: R8's global_load_lds staging, but with the T3/T4 pipeline:
// 3-slot LDS ring, counted s_waitcnt vmcnt(N) (never 0 mid-loop), raw
// s_barrier. R8's __syncthreads drained vmcnt(0) every z-step, eating
// the full HBM latency per iteration. Now slice k is staged ~2 iterations
// before use and stays in flight across barriers.
//
// vmcnt ledger (retires in issue order; stores count too):
//   per wave: stage = 5 gload_lds (20 rows, 1 row/instr, 41 lanes x 16B),
//   stores = 5/iter. At iter i wait: suffix = stage(i+1)5, st(i-2)5,
//   stage(i+2)5, st(i-1)5 -> vmcnt(10) retires exactly through stage(i+1).
//   Iter 0 (no stores outstanding yet): vmcnt(5).
// WAR safety: slot written by stage(i+3) was last read at iter i-1 (all
// reads consumed before iter i's barrier).

typedef float f32x2 __attribute__((ext_vector_type(2)));

static constexpr int Dd = 160, Hh = 192, Ww = 160, BC = 4;
static constexpr int Zt = 8, Yt = 16;
static constexpr int NZB = Dd / Zt;   // 20
static constexpr int NYB = Hh / Yt;   // 12
static constexpr float KW1 = 1.0f / 6.0f;
static constexpr float KW0 = 2.0f / 3.0f;

// LDS row: 164 floats = 656 B = 41*16 B (one gload16 instr per row, 41 lanes:
// lane 0 fills the 4-float front pad from w=0..3, lanes 1..40 fill w=0..159).
static constexpr int ROWF   = 164;
static constexpr int PROWS  = 20;            // 18 used + 2 dummy (uniform 5/wave)
static constexpr int PATCHF = PROWS * ROWF;  // 3280 floats = 13120 B

#define VMCNT(n) asm volatile("s_waitcnt vmcnt(" #n ")" ::: "memory")
#define BAR()    __builtin_amdgcn_s_barrier()

__device__ __forceinline__ void gload16(const float* g, float* l) {
    __builtin_amdgcn_global_load_lds(
        (const __attribute__((address_space(1))) float*)g,
        (__attribute__((address_space(3))) float*)l, 16, 0, 0);
}

struct YF { float v[12]; };   // y-filtered row at w = 10wc-1 .. 10wc+10

__global__ __launch_bounds__(256, 4) void CoeffToValue_kernel(
    const float* __restrict__ in, float* __restrict__ out)
{
    __shared__ __align__(16) float lds[3 * PATCHF];

    const int tid  = threadIdx.x;
    const int lane = tid & 63;
    const int wave = tid >> 6;
    const int wc   = tid & 15;     // w-chunk: outputs [10wc, 10wc+10)
    const int yo   = tid >> 4;     // y-output within tile: 0..15

    const int bid = blockIdx.x;
    const int zc  = bid % NZB;
    const int yb  = (bid / NZB) % NYB;
    const int bc  = bid / (NZB * NYB);
    const int z0  = zc * Zt;
    const int y0  = yb * Yt;

    // y-tap weights; zero boundary folded into weights (clamped rows finite).
    float cyw[3];
    {
        const float wy[3] = {KW1, KW0, KW1};
#pragma unroll
        for (int dy = 0; dy < 3; ++dy) {
            const int g = y0 + yo + dy - 1;
            cyw[dy] = (g >= 0 && g < Hh) ? wy[dy] : 0.0f;
        }
    }

    const size_t plane = (size_t)Hh * Ww;
    const float* inb = in + (size_t)bc * Dd * plane;

    // per-lane global w-offset for row staging (lane 0 feeds the front pad)
    const int woff = (lane == 0) ? 0 : 4 * (lane - 1);

    // Stage slice z0+k into ring slot (k+3)%3: 5 instr/wave, 1 row each.
    auto stage = [&](int k) {
        int zs = z0 + k;
        zs = zs < 0 ? 0 : (zs >= Dd ? Dd - 1 : zs);
        const float* sp = inb + (size_t)zs * plane;
        float* slot = lds + ((k + 3) % 3) * PATCHF;
        if (lane < 41) {
#pragma unroll
            for (int r = 0; r < 5; ++r) {
                const int p  = wave + 4 * r;          // LDS row 0..19
                const int ps = p > 17 ? 17 : p;       // dummy rows re-read row 17
                int ys = y0 - 1 + ps;
                ys = ys < 0 ? 0 : (ys >= Hh ? Hh - 1 : ys);
                gload16(sp + (size_t)ys * Ww + woff, slot + p * ROWF);
            }
        }
    };

    // y-filter slice z0+k at (yo, wc) from LDS into registers.
    auto yfilter = [&](int k) -> YF {
        const float* base = lds + ((k + 3) % 3) * PATCHF + 10 * wc + 2;
        YF o;
#pragma unroll
        for (int q = 0; q < 12; ++q) o.v[q] = 0.0f;
#pragma unroll
        for (int dy = 0; dy < 3; ++dy) {
            const float* rp = base + (yo + dy) * ROWF;
            float v[14];
#pragma unroll
            for (int r = 0; r < 7; ++r) {
                f32x2 p2 = *reinterpret_cast<const f32x2*>(rp + 2 * r);
                v[2 * r] = p2.x; v[2 * r + 1] = p2.y;
            }
            const float c = cyw[dy];
#pragma unroll
            for (int q = 0; q < 12; ++q) o.v[q] = fmaf(c, v[q + 1], o.v[q]);
        }
        return o;
    };

    // --- prologue: slices -1,0,1 staged; yf ring primed; slice 2 issued ---
    stage(-1); stage(0); stage(1);          // 15 outstanding
    VMCNT(10); BAR();                       // stage(-1) landed (all waves)
    YF a = yfilter(-1);
    VMCNT(5); BAR();                        // stage(0) landed; slot2 reads done
    stage(2);                               // reuses slice -1's slot
    YF b = yfilter(0);

#pragma unroll
    for (int i = 0; i < Zt; ++i) {
        if (i == 0) { VMCNT(5); } else { VMCNT(10); }   // stage(i+1) landed
        BAR();                                          // block-wide
        if (i <= Zt - 3) stage(i + 3);      // into slice i's slot (reads sealed)
        YF n = yfilter(i + 1);

        const int z = z0 + i;
        const float czm = (z > 0)      ? KW1 : 0.0f;
        const float czp = (z < Dd - 1) ? KW1 : 0.0f;

        float t[12];
#pragma unroll
        for (int q = 0; q < 12; ++q)
            t[q] = fmaf(czm, a.v[q], fmaf(KW0, b.v[q], czp * n.v[q]));
        // w-boundary: select (not multiply) so pad garbage cannot leak
        t[0]  = (wc > 0)  ? t[0]  : 0.0f;
        t[11] = (wc < 15) ? t[11] : 0.0f;

        float* orow = out + ((size_t)(bc * Dd + z) * Hh + (y0 + yo)) * Ww + 10 * wc;
#pragma unroll
        for (int s = 0; s < 5; ++s) {
            f32x2 o2;
            o2.x = fmaf(KW0, t[2 * s + 1], KW1 * (t[2 * s]     + t[2 * s + 2]));
            o2.y = fmaf(KW0, t[2 * s + 2], KW1 * (t[2 * s + 1] + t[2 * s + 3]));
            *reinterpret_cast<f32x2*>(orow + 2 * s) = o2;
        }

        a = b; b = n;                       // reg-resident yf ring rotate
    }
}

extern "C" void kernel_launch(void* const* d_in, const int* in_sizes, int n_in,
                              void* d_out, int out_size, void* d_ws, size_t ws_size,
                              hipStream_t stream) {
    const float* in = (const float*)d_in[0];
    float* out = (float*)d_out;

    const int blocks = BC * NYB * NZB;   // 4*12*20 = 960 (whole grid co-resident)
    CoeffToValue_kernel<<<blocks, 256, 0, stream>>>(in, out);
}